// Round 3
// baseline (41.425 us; speedup 1.0000x reference)
//
#include <hip/hip_runtime.h>
#include <math.h>

#define IN_DIM  512
#define OUT_DIM 512
#define BATCH   2
#define NPTS    50000
#define TOTAL   (BATCH * NPTS)
#define RPW     16                       // rows per wave in kernel 2 (50000 % 16 == 0 per batch... 50000/16=3125 exact)
#define NWAVES  (TOTAL / RPW)            // 6250 identical waves

typedef float f4 __attribute__((ext_vector_type(4)));

__device__ __forceinline__ f4 ntload(const f4* p) {
    return __builtin_nontemporal_load(p);
}

__device__ __forceinline__ float dot8(f4 a0, f4 a1, f4 b0, f4 b1) {
    return a0[0]*b0[0] + a0[1]*b0[1] + a0[2]*b0[2] + a0[3]*b0[3]
         + a1[0]*b1[0] + a1[1]*b1[1] + a1[2]*b1[2] + a1[3]*b1[3];
}

__device__ __forceinline__ float wred(float x) {
    #pragma unroll
    for (int off = 32; off; off >>= 1) x += __shfl_xor(x, off);
    return x;
}

__device__ __forceinline__ float sigmoidf(float x) {
    return 1.0f / (1.0f + __expf(-x));
}

// Kernel 1: v[b][d] = sum_e mat[d][e] * s[b][e]   (v: [2][512] f32 in d_ws)
// 1024 waves, one per (b,d). s is 4 KB -> L2-resident, mat rows coalesced f4.
__global__ __launch_bounds__(256) void dgi_compute_v(
    const float* __restrict__ mat, const float* __restrict__ s,
    float* __restrict__ v)
{
    const int lane = threadIdx.x & 63;
    const int W    = (int)((blockIdx.x * blockDim.x + threadIdx.x) >> 6);
    const int b    = W >> 9;
    const int d    = W & 511;

    const f4* mrow = reinterpret_cast<const f4*>(mat + (size_t)d * OUT_DIM);
    const f4* srow = reinterpret_cast<const f4*>(s   + (size_t)b * OUT_DIM);
    const f4 m0 = mrow[lane], m1 = mrow[lane + 64];
    const f4 s0 = srow[lane], s1 = srow[lane + 64];

    float acc = wred(dot8(m0, m1, s0, s1));
    if (lane == 0) v[b * IN_DIM + d] = acc;
}

// Kernel 2: out[row] = sigmoid( z[row,:] . v[b,:] ), b = row >= NPTS.
// 6250 identical waves, 16 contiguous rows (32 KB) each; batch never changes
// within a wave. 2-stage software pipeline: next pair's 4 float4 loads issue
// before the current pair's reduce, keeping the memory pipe busy through the
// shuffle chain. Fully unrolled; VGPR pinned <=64 for 32 waves/CU.
__global__ __launch_bounds__(256, 8) void dgi_score(
    const float* __restrict__ z, const float* __restrict__ v,
    float* __restrict__ out)
{
    const int lane = threadIdx.x & 63;
    const int wid  = (int)((blockIdx.x * blockDim.x + threadIdx.x) >> 6);
    if (wid >= NWAVES) return;

    const long r0 = (long)wid * RPW;          // 16 contiguous rows, single batch
    const int  b  = (r0 >= NPTS);

    const f4* vr = reinterpret_cast<const f4*>(v + (size_t)b * IN_DIM);
    const f4 v0 = vr[lane], v1 = vr[lane + 64];

    const f4* zp = reinterpret_cast<const f4*>(z + r0 * IN_DIM);  // row = 128 f4

    // prologue: rows 0,1 in flight
    f4 a0 = ntload(zp + lane),        a1 = ntload(zp + lane + 64);
    f4 c0 = ntload(zp + 128 + lane),  c1 = ntload(zp + 128 + lane + 64);

    #pragma unroll
    for (int i = 0; i < RPW; i += 2) {
        f4 n0, n1, n2, n3;
        if (i + 2 < RPW) {                     // issue next pair before reducing
            const f4* znA = zp + (i + 2) * 128;
            const f4* znB = zp + (i + 3) * 128;
            n0 = ntload(znA + lane);  n1 = ntload(znA + lane + 64);
            n2 = ntload(znB + lane);  n3 = ntload(znB + lane + 64);
        }
        float accA = wred(dot8(a0, a1, v0, v1));
        float accB = wred(dot8(c0, c1, v0, v1));
        if (lane == 0) {
            out[r0 + i]     = sigmoidf(accA);
            out[r0 + i + 1] = sigmoidf(accB);
        }
        a0 = n0; a1 = n1; c0 = n2; c1 = n3;
    }
}

extern "C" void kernel_launch(void* const* d_in, const int* in_sizes, int n_in,
                              void* d_out, int out_size, void* d_ws, size_t ws_size,
                              hipStream_t stream) {
    const float* z   = (const float*)d_in[0];   // [2, 50000, 512] f32
    const float* s   = (const float*)d_in[1];   // [2, 512] f32
    const float* mat = (const float*)d_in[2];   // [512, 512] f32
    float* out = (float*)d_out;                 // [2, 50000] f32
    float* v   = (float*)d_ws;                  // [2, 512] f32 scratch

    dgi_compute_v<<<BATCH * 128, 256, 0, stream>>>(mat, s, v);

    const int blocks = (NWAVES + 3) / 4;        // 4 waves per 256-thread block
    dgi_score<<<blocks, 256, 0, stream>>>(z, v, out);
}

// Round 4
// 41.279 us; speedup vs baseline: 1.0035x; 1.0035x over previous
//
#include <hip/hip_runtime.h>
#include <math.h>

#define IN_DIM  512
#define OUT_DIM 512
#define BATCH   2
#define NPTS    50000
#define TOTAL   (BATCH * NPTS)
#define RPW     16                       // 50000 % 16 == 0 -> every wave batch-uniform
#define NWAVES  (TOTAL / RPW)            // 6250 identical waves

typedef float f4 __attribute__((ext_vector_type(4)));

__device__ __forceinline__ f4 ntload(const f4* p) {
    return __builtin_nontemporal_load(p);
}

__device__ __forceinline__ float dot8(f4 a0, f4 a1, f4 b0, f4 b1) {
    return a0[0]*b0[0] + a0[1]*b0[1] + a0[2]*b0[2] + a0[3]*b0[3]
         + a1[0]*b1[0] + a1[1]*b1[1] + a1[2]*b1[2] + a1[3]*b1[3];
}

__device__ __forceinline__ float wred(float x) {
    #pragma unroll
    for (int off = 32; off; off >>= 1) x += __shfl_xor(x, off);
    return x;   // full sum present in ALL lanes (xor butterfly)
}

__device__ __forceinline__ float sigmoidf(float x) {
    return 1.0f / (1.0f + __expf(-x));
}

// Kernel 1: v[b][d] = sum_e mat[d][e] * s[b][e]   (v: [2][512] f32 in d_ws)
// 1024 waves, one per (b,d). s is 4 KB -> L2-resident, mat rows coalesced f4.
__global__ __launch_bounds__(256) void dgi_compute_v(
    const float* __restrict__ mat, const float* __restrict__ s,
    float* __restrict__ v)
{
    const int lane = threadIdx.x & 63;
    const int W    = (int)((blockIdx.x * blockDim.x + threadIdx.x) >> 6);
    const int b    = W >> 9;
    const int d    = W & 511;

    const f4* mrow = reinterpret_cast<const f4*>(mat + (size_t)d * OUT_DIM);
    const f4* srow = reinterpret_cast<const f4*>(s   + (size_t)b * OUT_DIM);
    const f4 m0 = mrow[lane], m1 = mrow[lane + 64];
    const f4 s0 = srow[lane], s1 = srow[lane + 64];

    float acc = wred(dot8(m0, m1, s0, s1));
    if (lane == 0) v[b * IN_DIM + d] = acc;
}

// Kernel 2: out[row] = sigmoid( z[row,:] . v[b,:] ), b = row >= NPTS.
// 6250 identical waves x 16 contiguous rows (32 KB streamed per wave).
// Groups of 4 rows: 8 independent float4 loads, 4 independent reduce chains;
// compiler schedules/pipelines across the unrolled groups (R1 showed the
// plain-loop compiler schedule beats a hand pipeline + VGPR cap).
__global__ __launch_bounds__(256) void dgi_score(
    const float* __restrict__ z, const float* __restrict__ v,
    float* __restrict__ out)
{
    const int lane = threadIdx.x & 63;
    const int wid  = (int)((blockIdx.x * blockDim.x + threadIdx.x) >> 6);
    if (wid >= NWAVES) return;

    const long r0 = (long)wid * RPW;         // 16 contiguous rows, one batch
    const int  b  = (r0 >= NPTS);

    const f4* vr = reinterpret_cast<const f4*>(v + (size_t)b * IN_DIM);
    const f4 v0 = vr[lane], v1 = vr[lane + 64];

    const f4* zp = reinterpret_cast<const f4*>(z + r0 * IN_DIM);  // row = 128 f4

    #pragma unroll
    for (int i = 0; i < RPW; i += 4) {
        const f4* zA = zp + (i + 0) * 128;
        const f4* zB = zp + (i + 1) * 128;
        const f4* zC = zp + (i + 2) * 128;
        const f4* zD = zp + (i + 3) * 128;
        const f4 a0 = ntload(zA + lane), a1 = ntload(zA + lane + 64);
        const f4 b0 = ntload(zB + lane), b1 = ntload(zB + lane + 64);
        const f4 c0 = ntload(zC + lane), c1 = ntload(zC + lane + 64);
        const f4 d0 = ntload(zD + lane), d1 = ntload(zD + lane + 64);

        const float rA = wred(dot8(a0, a1, v0, v1));
        const float rB = wred(dot8(b0, b1, v0, v1));
        const float rC = wred(dot8(c0, c1, v0, v1));
        const float rD = wred(dot8(d0, d1, v0, v1));

        // packed epilogue: lanes 0-3 store the 4 results (one 16B store)
        float r = (lane == 0) ? rA : (lane == 1) ? rB : (lane == 2) ? rC : rD;
        if (lane < 4) out[r0 + i + lane] = sigmoidf(r);
    }
}

extern "C" void kernel_launch(void* const* d_in, const int* in_sizes, int n_in,
                              void* d_out, int out_size, void* d_ws, size_t ws_size,
                              hipStream_t stream) {
    const float* z   = (const float*)d_in[0];   // [2, 50000, 512] f32
    const float* s   = (const float*)d_in[1];   // [2, 512] f32
    const float* mat = (const float*)d_in[2];   // [512, 512] f32
    float* out = (float*)d_out;                 // [2, 50000] f32
    float* v   = (float*)d_ws;                  // [2, 512] f32 scratch

    dgi_compute_v<<<BATCH * 128, 256, 0, stream>>>(mat, s, v);

    const int blocks = (NWAVES + 3) / 4;        // 1563 blocks, 4 waves each
    dgi_score<<<blocks, 256, 0, stream>>>(z, v, out);
}

// Round 5
// 39.183 us; speedup vs baseline: 1.0572x; 1.0535x over previous
//
#include <hip/hip_runtime.h>
#include <math.h>

#define IN_DIM  512
#define OUT_DIM 512
#define BATCH   2
#define NPTS    50000
#define TOTAL   (BATCH * NPTS)
#define RPW     14                      // rows per wave in kernel 2 (R1 measured-best)

typedef float f4 __attribute__((ext_vector_type(4)));

__device__ __forceinline__ float dot8(f4 a0, f4 a1, f4 b0, f4 b1) {
    return a0[0]*b0[0] + a0[1]*b0[1] + a0[2]*b0[2] + a0[3]*b0[3]
         + a1[0]*b1[0] + a1[1]*b1[1] + a1[2]*b1[2] + a1[3]*b1[3];
}

__device__ __forceinline__ float wred(float x) {
    #pragma unroll
    for (int off = 32; off; off >>= 1) x += __shfl_xor(x, off);
    return x;
}

// Kernel 1: v[b][d] = sum_e mat[d][e] * s[b][e]   (v: [2][512] f32 in d_ws)
// 1024 waves, one per (b,d). s is 4 KB -> L2-resident, mat rows coalesced f4.
__global__ __launch_bounds__(256) void dgi_compute_v(
    const float* __restrict__ mat, const float* __restrict__ s,
    float* __restrict__ v)
{
    const int lane = threadIdx.x & 63;
    const int W    = (int)((blockIdx.x * blockDim.x + threadIdx.x) >> 6);
    const int b    = W >> 9;
    const int d    = W & 511;

    const f4* mrow = reinterpret_cast<const f4*>(mat + (size_t)d * OUT_DIM);
    const f4* srow = reinterpret_cast<const f4*>(s   + (size_t)b * OUT_DIM);
    const f4 m0 = mrow[lane], m1 = mrow[lane + 64];
    const f4 s0 = srow[lane], s1 = srow[lane + 64];

    float acc = wred(dot8(m0, m1, s0, s1));
    if (lane == 0) v[b * IN_DIM + d] = acc;
}

// Kernel 2: out[row] = sigmoid( z[row,:] . v[b,:] ), b = row >= NPTS.
// R1-exact structure (measured best, 38.7us) with one change: PLAIN loads
// instead of nontemporal, so z (204.8 MB < 256 MB Infinity Cache) stays
// L3-resident across graph replays instead of being re-fetched from HBM.
__global__ __launch_bounds__(256) void dgi_score(
    const float* __restrict__ z, const float* __restrict__ v,
    float* __restrict__ out)
{
    const int lane = threadIdx.x & 63;
    const int wave = (int)((blockIdx.x * blockDim.x + threadIdx.x) >> 6);
    const long base = (long)wave * RPW;
    if (base >= TOTAL) return;
    const int cnt = (TOTAL - base < RPW) ? (int)(TOTAL - base) : RPW;

    int b_cur = -1;
    f4 v0, v1;

    int i = 0;
    for (; i + 1 < cnt; i += 2) {
        const long rowA = base + i;
        const long rowB = rowA + 1;
        const f4* zA = reinterpret_cast<const f4*>(z + rowA * IN_DIM);
        const f4* zB = reinterpret_cast<const f4*>(z + rowB * IN_DIM);
        const f4 a0 = zA[lane], a1 = zA[lane + 64];
        const f4 c0 = zB[lane], c1 = zB[lane + 64];

        const int bA = (rowA >= NPTS);
        if (bA != b_cur) {
            b_cur = bA;
            const f4* vr = reinterpret_cast<const f4*>(v + (size_t)bA * IN_DIM);
            v0 = vr[lane]; v1 = vr[lane + 64];
        }
        float accA = dot8(a0, a1, v0, v1);

        const int bB = (rowB >= NPTS);
        if (bB != b_cur) {
            b_cur = bB;
            const f4* vr = reinterpret_cast<const f4*>(v + (size_t)bB * IN_DIM);
            v0 = vr[lane]; v1 = vr[lane + 64];
        }
        float accB = dot8(c0, c1, v0, v1);

        accA = wred(accA);
        accB = wred(accB);
        if (lane == 0) {
            out[rowA] = 1.0f / (1.0f + __expf(-accA));
            out[rowB] = 1.0f / (1.0f + __expf(-accB));
        }
    }
    if (i < cnt) {
        const long row = base + i;
        const f4* zr = reinterpret_cast<const f4*>(z + row * IN_DIM);
        const f4 a0 = zr[lane], a1 = zr[lane + 64];
        const int b = (row >= NPTS);
        if (b != b_cur) {
            const f4* vr = reinterpret_cast<const f4*>(v + (size_t)b * IN_DIM);
            v0 = vr[lane]; v1 = vr[lane + 64];
        }
        float acc = wred(dot8(a0, a1, v0, v1));
        if (lane == 0) out[row] = 1.0f / (1.0f + __expf(-acc));
    }
}

extern "C" void kernel_launch(void* const* d_in, const int* in_sizes, int n_in,
                              void* d_out, int out_size, void* d_ws, size_t ws_size,
                              hipStream_t stream) {
    const float* z   = (const float*)d_in[0];   // [2, 50000, 512] f32
    const float* s   = (const float*)d_in[1];   // [2, 512] f32
    const float* mat = (const float*)d_in[2];   // [512, 512] f32
    float* out = (float*)d_out;                 // [2, 50000] f32
    float* v   = (float*)d_ws;                  // [2, 512] f32 scratch

    dgi_compute_v<<<BATCH * 128, 256, 0, stream>>>(mat, s, v);

    const int nwaves = (TOTAL + RPW - 1) / RPW;         // 7143
    const int blocks = (nwaves + 3) / 4;                // 1786
    dgi_score<<<blocks, 256, 0, stream>>>(z, v, out);
}